// Round 16
// baseline (35290.781 us; speedup 1.0000x reference)
//
#include <hip/hip_runtime.h>

#define T_SEQ 8192
#define HDIM  2048
#define EDIM  2048
#define RBLK  64                      // recurrence blocks (forced by VGPR capacity)
#define ROWS_PER_BLK (HDIM / RBLK)    // 32 rows/block, 4 rows/wave

typedef unsigned long long u64;
typedef __attribute__((ext_vector_type(4))) unsigned int u32x4;
typedef __attribute__((ext_vector_type(4))) float f32x4;

// two 16B agent-coherent loads + full drain (R13 proven poll, f32 exchange)
__device__ inline void poll_pair(const u64* p0, const u64* p1, u32x4& a, u32x4& b) {
    asm volatile("global_load_dwordx4 %0, %2, off sc1\n\t"
                 "global_load_dwordx4 %1, %3, off sc1\n\t"
                 "s_waitcnt vmcnt(0)"
                 : "=v"(a), "=v"(b) : "v"(p0), "v"(p1) : "memory");
}

// Non-rematerializable 16B load: result MUST live in registers (asm output).
__device__ inline f32x4 ld_w16(const float* p) {
    f32x4 r;
    asm volatile("global_load_dwordx4 %0, %1, off" : "=v"(r) : "v"(p));
    return r;
}

// tanh via e^{2z}: clamp +-15, exp2, rcp (validated R8-R15: absmax unchanged)
__device__ inline float fast_tanh(float z) {
    float zc = fminf(fmaxf(z, -15.f), 15.f);
    float zs = zc * 2.88539008177792681f;   // 2*log2(e)
    float ez; asm("v_exp_f32 %0, %1" : "=v"(ez) : "v"(zs));
    float rc; float ezp = ez + 1.f;
    asm("v_rcp_f32 %0, %1" : "=v"(rc) : "v"(ezp));
    return (ez - 1.f) * rc;
}

// ---------------------------------------------------------------------------
// 128x128-tile GEMM (NT), TRANSPOSED output: Ct[n][m] = A@B^T + bias (R13).
// Used for xpT (16 recurrence steps per cache line).
// ---------------------------------------------------------------------------
__global__ __launch_bounds__(256) void gemm128_nt_bias_tc(
    const float* __restrict__ A, const float* __restrict__ B,
    const float* __restrict__ bias, float* __restrict__ Ct,
    int M, int N, int K)
{
    __shared__ float As[16][128 + 4];
    __shared__ float Bs[16][128 + 4];

    const int tid = threadIdx.x;
    const int tx = tid & 15;
    const int ty = tid >> 4;
    const int m0 = blockIdx.y * 128;
    const int n0 = blockIdx.x * 128;

    float acc[8][8] = {};

    for (int kk = 0; kk < K; kk += 16) {
        #pragma unroll
        for (int p = 0; p < 2; ++p) {
            int idx = p * 256 + tid;
            int r  = idx >> 2;
            int cb = (idx & 3) * 4;
            float4 va = *(const float4*)&A[(size_t)(m0 + r) * K + kk + cb];
            As[cb + 0][r] = va.x; As[cb + 1][r] = va.y;
            As[cb + 2][r] = va.z; As[cb + 3][r] = va.w;
            float4 vb = *(const float4*)&B[(size_t)(n0 + r) * K + kk + cb];
            Bs[cb + 0][r] = vb.x; Bs[cb + 1][r] = vb.y;
            Bs[cb + 2][r] = vb.z; Bs[cb + 3][r] = vb.w;
        }
        __syncthreads();
        #pragma unroll
        for (int k = 0; k < 16; ++k) {
            float4 a0 = *(const float4*)&As[k][ty * 8];
            float4 a1 = *(const float4*)&As[k][ty * 8 + 4];
            float4 b0 = *(const float4*)&Bs[k][tx * 8];
            float4 b1 = *(const float4*)&Bs[k][tx * 8 + 4];
            float av[8] = {a0.x, a0.y, a0.z, a0.w, a1.x, a1.y, a1.z, a1.w};
            float bv[8] = {b0.x, b0.y, b0.z, b0.w, b1.x, b1.y, b1.z, b1.w};
            #pragma unroll
            for (int i = 0; i < 8; ++i)
                #pragma unroll
                for (int j = 0; j < 8; ++j)
                    acc[i][j] = fmaf(av[i], bv[j], acc[i][j]);
        }
        __syncthreads();
    }

    #pragma unroll
    for (int j = 0; j < 8; ++j) {
        float bb = bias[n0 + tx * 8 + j];
        float4 o0, o1;
        o0.x = acc[0][j] + bb; o0.y = acc[1][j] + bb;
        o0.z = acc[2][j] + bb; o0.w = acc[3][j] + bb;
        o1.x = acc[4][j] + bb; o1.y = acc[5][j] + bb;
        o1.z = acc[6][j] + bb; o1.w = acc[7][j] + bb;
        float* cp = &Ct[(size_t)(n0 + tx * 8 + j) * M + m0 + ty * 8];
        *(float4*)cp = o0;
        *(float4*)(cp + 4) = o1;
    }
}

// ---------------------------------------------------------------------------
// Recurrence + FUSED output projection (R16).
//   Core sync/dot identical to R13 (proven 12.7ms): f32 tagged-word exchange,
//   hbuf[2][HDIM] u64 (tag<<32|f32bits), 2x dwordx4 sc1 poll, xchg writers.
//   NEW: after the tagged store of h_{t+1}, the block computes logits row t-1
//   for ITS 32 columns (c = r0..r0+31, same indices as its rows) from the
//   full h_{t-1} still in LDS — mirror of the W_h dot but with Wy streamed
//   from L2 (256KB/block slice, 2MB/XCD => L2-resident). This work sits in
//   the poll-wait bubble (VALUBusy was 11%) and is OFF the inter-block
//   critical path. Hs store eliminated (nothing consumed it); h_final
//   written directly at t=T-1; epilogue poll (tag T) yields row T-1.
//   hsm double-buffered: wave A's overwrite of hsm[p] at iter t+2 is gated
//   by poll success on tag t+2, which requires every wave's tag-(t+2) store,
//   which (program order) follows that wave's iter-t logits read of hsm[p].
// ---------------------------------------------------------------------------
__global__ __launch_bounds__(512, 1) void rnn_recurrence(
    const float* __restrict__ Wh, const float* __restrict__ Wy,
    const float* __restrict__ By, const float* __restrict__ xpT,
    float* __restrict__ hfinal, float* __restrict__ logits,
    u64* __restrict__ hbuf, int T)
{
    const int tid  = threadIdx.x;
    const int lane = tid & 63;
    const int wid  = tid >> 6;                              // 0..7
    const int r0   = blockIdx.x * ROWS_PER_BLK + wid * 4;   // wave's rows & logit cols

    const float* wr0 = Wh + (size_t)(r0 + 0) * HDIM + lane * 4;
    const float* wr1 = Wh + (size_t)(r0 + 1) * HDIM + lane * 4;
    const float* wr2 = Wh + (size_t)(r0 + 2) * HDIM + lane * 4;
    const float* wr3 = Wh + (size_t)(r0 + 3) * HDIM + lane * 4;

    f32x4 w00 = ld_w16(wr0 + 0*256), w01 = ld_w16(wr0 + 1*256), w02 = ld_w16(wr0 + 2*256), w03 = ld_w16(wr0 + 3*256);
    f32x4 w04 = ld_w16(wr0 + 4*256), w05 = ld_w16(wr0 + 5*256), w06 = ld_w16(wr0 + 6*256), w07 = ld_w16(wr0 + 7*256);
    f32x4 w10 = ld_w16(wr1 + 0*256), w11 = ld_w16(wr1 + 1*256), w12 = ld_w16(wr1 + 2*256), w13 = ld_w16(wr1 + 3*256);
    f32x4 w14 = ld_w16(wr1 + 4*256), w15 = ld_w16(wr1 + 5*256), w16 = ld_w16(wr1 + 6*256), w17 = ld_w16(wr1 + 7*256);
    f32x4 w20 = ld_w16(wr2 + 0*256), w21 = ld_w16(wr2 + 1*256), w22 = ld_w16(wr2 + 2*256), w23 = ld_w16(wr2 + 3*256);
    f32x4 w24 = ld_w16(wr2 + 4*256), w25 = ld_w16(wr2 + 5*256), w26 = ld_w16(wr2 + 6*256), w27 = ld_w16(wr2 + 7*256);
    f32x4 w30 = ld_w16(wr3 + 0*256), w31 = ld_w16(wr3 + 1*256), w32 = ld_w16(wr3 + 2*256), w33 = ld_w16(wr3 + 3*256);
    f32x4 w34 = ld_w16(wr3 + 4*256), w35 = ld_w16(wr3 + 5*256), w36 = ld_w16(wr3 + 6*256), w37 = ld_w16(wr3 + 7*256);
    asm volatile("s_waitcnt vmcnt(0)" ::: "memory");

    const float* wy0 = Wy + (size_t)(r0 + 0) * HDIM + lane * 4;
    const float* wy1 = Wy + (size_t)(r0 + 1) * HDIM + lane * 4;
    const float* wy2 = Wy + (size_t)(r0 + 2) * HDIM + lane * 4;
    const float* wy3 = Wy + (size_t)(r0 + 3) * HDIM + lane * 4;
    const float byq = (lane < 4) ? By[r0 + lane] : 0.f;

    __shared__ float hsm[2][HDIM];   // double-buffered full-h stage

    #define WH_DOT(HP)                                                          \
        float s0 = 0.f, s1 = 0.f, s2 = 0.f, s3 = 0.f;                           \
        {                                                                       \
        _Pragma("unroll")                                                       \
        for (int t8 = 0; t8 < 8; ++t8) {                                        \
            float4 h4 = ((const float4*)(HP))[t8 * 64 + lane];                  \
            const f32x4* wp = (t8==0)? &w00 : (t8==1)? &w01 : (t8==2)? &w02 :   \
                              (t8==3)? &w03 : (t8==4)? &w04 : (t8==5)? &w05 :   \
                              (t8==6)? &w06 : &w07;                             \
            (void)wp;                                                           \
        }                                                                       \
        }

    #undef WH_DOT

    for (int t = 0; t < T; ++t) {
        float xq = 0.f;
        if (lane < 4) xq = xpT[(size_t)(r0 + lane) * T + t];

        float sv = 0.f;
        if (t > 0) {
            const u64* hb = hbuf + (size_t)(t & 1) * HDIM;
            const unsigned tg = (unsigned)t;
            const u64* p0 = hb + 2 * tid;
            const u64* p1 = hb + 1024 + 2 * tid;

            u32x4 a, b;
            poll_pair(p0, p1, a, b);
            while ((a.y != tg) | (a.w != tg) | (b.y != tg) | (b.w != tg))
                poll_pair(p0, p1, a, b);

            float* hp = hsm[t & 1];
            ((float2*)hp)[tid] =
                make_float2(__uint_as_float(a.x), __uint_as_float(a.z));
            ((float2*)hp)[tid + 512] =
                make_float2(__uint_as_float(b.x), __uint_as_float(b.z));
            __syncthreads();

            float s0 = 0.f, s1 = 0.f, s2 = 0.f, s3 = 0.f;
            #define RNN_STEP(IDX, WA, WB, WC, WD)                                   \
            {   float4 h4 = ((const float4*)hp)[(IDX) * 64 + lane];                 \
                s0 = fmaf(WA.x, h4.x, s0); s0 = fmaf(WA.y, h4.y, s0);               \
                s0 = fmaf(WA.z, h4.z, s0); s0 = fmaf(WA.w, h4.w, s0);               \
                s1 = fmaf(WB.x, h4.x, s1); s1 = fmaf(WB.y, h4.y, s1);               \
                s1 = fmaf(WB.z, h4.z, s1); s1 = fmaf(WB.w, h4.w, s1);               \
                s2 = fmaf(WC.x, h4.x, s2); s2 = fmaf(WC.y, h4.y, s2);               \
                s2 = fmaf(WC.z, h4.z, s2); s2 = fmaf(WC.w, h4.w, s2);               \
                s3 = fmaf(WD.x, h4.x, s3); s3 = fmaf(WD.y, h4.y, s3);               \
                s3 = fmaf(WD.z, h4.z, s3); s3 = fmaf(WD.w, h4.w, s3); }
            RNN_STEP(0, w00, w10, w20, w30)
            RNN_STEP(1, w01, w11, w21, w31)
            RNN_STEP(2, w02, w12, w22, w32)
            RNN_STEP(3, w03, w13, w23, w33)
            RNN_STEP(4, w04, w14, w24, w34)
            RNN_STEP(5, w05, w15, w25, w35)
            RNN_STEP(6, w06, w16, w26, w36)
            RNN_STEP(7, w07, w17, w27, w37)
            #undef RNN_STEP

            float fa = (lane & 1) ? s1 : s0;
            float fb = (lane & 1) ? s0 : s1;
            fa += __shfl_xor(fb, 1);
            float fc = (lane & 1) ? s3 : s2;
            float fd = (lane & 1) ? s2 : s3;
            fc += __shfl_xor(fd, 1);
            float fe = (lane & 2) ? fc : fa;
            float ff = (lane & 2) ? fa : fc;
            fe += __shfl_xor(ff, 2);
            #pragma unroll
            for (int off = 4; off < 64; off <<= 1) fe += __shfl_xor(fe, off);
            sv = fe;
        }

        float hn = fast_tanh(sv + xq);
        if (lane < 4) {
            u64 pk = ((u64)(unsigned)(t + 1) << 32) | (u64)__float_as_uint(hn);
            (void)__hip_atomic_exchange(
                &hbuf[(size_t)((t + 1) & 1) * HDIM + r0 + lane], pk,
                __ATOMIC_RELAXED, __HIP_MEMORY_SCOPE_AGENT);
            if (t == T - 1) hfinal[r0 + lane] = hn;
        }

        // ---- fused output projection: logits row t-1 from hsm[t&1] ----
        if (t > 0) {
            const float* hp = hsm[t & 1];
            float q0 = 0.f, q1 = 0.f, q2 = 0.f, q3 = 0.f;
            #pragma unroll
            for (int t8 = 0; t8 < 8; ++t8) {
                float4 h4 = ((const float4*)hp)[t8 * 64 + lane];
                float4 y0 = *(const float4*)(wy0 + t8 * 256);
                float4 y1 = *(const float4*)(wy1 + t8 * 256);
                float4 y2 = *(const float4*)(wy2 + t8 * 256);
                float4 y3 = *(const float4*)(wy3 + t8 * 256);
                q0 = fmaf(y0.x, h4.x, q0); q0 = fmaf(y0.y, h4.y, q0);
                q0 = fmaf(y0.z, h4.z, q0); q0 = fmaf(y0.w, h4.w, q0);
                q1 = fmaf(y1.x, h4.x, q1); q1 = fmaf(y1.y, h4.y, q1);
                q1 = fmaf(y1.z, h4.z, q1); q1 = fmaf(y1.w, h4.w, q1);
                q2 = fmaf(y2.x, h4.x, q2); q2 = fmaf(y2.y, h4.y, q2);
                q2 = fmaf(y2.z, h4.z, q2); q2 = fmaf(y2.w, h4.w, q2);
                q3 = fmaf(y3.x, h4.x, q3); q3 = fmaf(y3.y, h4.y, q3);
                q3 = fmaf(y3.z, h4.z, q3); q3 = fmaf(y3.w, h4.w, q3);
            }
            float ga = (lane & 1) ? q1 : q0;
            float gb = (lane & 1) ? q0 : q1;
            ga += __shfl_xor(gb, 1);
            float gc = (lane & 1) ? q3 : q2;
            float gd = (lane & 1) ? q2 : q3;
            gc += __shfl_xor(gd, 1);
            float ge = (lane & 2) ? gc : ga;
            float gf = (lane & 2) ? ga : gc;
            ge += __shfl_xor(gf, 2);
            #pragma unroll
            for (int off = 4; off < 64; off <<= 1) ge += __shfl_xor(ge, off);
            if (lane < 4)
                logits[(size_t)(t - 1) * EDIM + r0 + lane] = ge + byq;
        }
    }

    // ---- epilogue: logits row T-1 from the tag-T values (buffer T&1) ----
    {
        const u64* hb = hbuf + (size_t)(T & 1) * HDIM;
        const unsigned tg = (unsigned)T;
        const u64* p0 = hb + 2 * tid;
        const u64* p1 = hb + 1024 + 2 * tid;

        u32x4 a, b;
        poll_pair(p0, p1, a, b);
        while ((a.y != tg) | (a.w != tg) | (b.y != tg) | (b.w != tg))
            poll_pair(p0, p1, a, b);

        float* hp = hsm[T & 1];
        ((float2*)hp)[tid] =
            make_float2(__uint_as_float(a.x), __uint_as_float(a.z));
        ((float2*)hp)[tid + 512] =
            make_float2(__uint_as_float(b.x), __uint_as_float(b.z));
        __syncthreads();

        float q0 = 0.f, q1 = 0.f, q2 = 0.f, q3 = 0.f;
        #pragma unroll
        for (int t8 = 0; t8 < 8; ++t8) {
            float4 h4 = ((const float4*)hp)[t8 * 64 + lane];
            float4 y0 = *(const float4*)(wy0 + t8 * 256);
            float4 y1 = *(const float4*)(wy1 + t8 * 256);
            float4 y2 = *(const float4*)(wy2 + t8 * 256);
            float4 y3 = *(const float4*)(wy3 + t8 * 256);
            q0 = fmaf(y0.x, h4.x, q0); q0 = fmaf(y0.y, h4.y, q0);
            q0 = fmaf(y0.z, h4.z, q0); q0 = fmaf(y0.w, h4.w, q0);
            q1 = fmaf(y1.x, h4.x, q1); q1 = fmaf(y1.y, h4.y, q1);
            q1 = fmaf(y1.z, h4.z, q1); q1 = fmaf(y1.w, h4.w, q1);
            q2 = fmaf(y2.x, h4.x, q2); q2 = fmaf(y2.y, h4.y, q2);
            q2 = fmaf(y2.z, h4.z, q2); q2 = fmaf(y2.w, h4.w, q2);
            q3 = fmaf(y3.x, h4.x, q3); q3 = fmaf(y3.y, h4.y, q3);
            q3 = fmaf(y3.z, h4.z, q3); q3 = fmaf(y3.w, h4.w, q3);
        }
        float ga = (lane & 1) ? q1 : q0;
        float gb = (lane & 1) ? q0 : q1;
        ga += __shfl_xor(gb, 1);
        float gc = (lane & 1) ? q3 : q2;
        float gd = (lane & 1) ? q2 : q3;
        gc += __shfl_xor(gd, 1);
        float ge = (lane & 2) ? gc : ga;
        float gf = (lane & 2) ? ga : gc;
        ge += __shfl_xor(gf, 2);
        #pragma unroll
        for (int off = 4; off < 64; off <<= 1) ge += __shfl_xor(ge, off);
        if (lane < 4)
            logits[(size_t)(T - 1) * EDIM + r0 + lane] = ge + byq;
    }
}

// ---------------------------------------------------------------------------
// Row softmax over EDIM=2048, IN-PLACE safe: all reads complete before the
// barrier-gated reductions; writes happen after.
// ---------------------------------------------------------------------------
__global__ __launch_bounds__(256) void softmax_rows(
    const float* __restrict__ logits, float* __restrict__ out)
{
    const int row = blockIdx.x;
    const float4* in4 = (const float4*)(logits + (size_t)row * EDIM);
    float4* out4 = (float4*)(out + (size_t)row * EDIM);

    float4 v0 = in4[threadIdx.x];
    float4 v1 = in4[threadIdx.x + 256];

    float m = fmaxf(fmaxf(fmaxf(v0.x, v0.y), fmaxf(v0.z, v0.w)),
                    fmaxf(fmaxf(v1.x, v1.y), fmaxf(v1.z, v1.w)));
    #pragma unroll
    for (int off = 32; off > 0; off >>= 1) m = fmaxf(m, __shfl_xor(m, off));

    __shared__ float red[4];
    if ((threadIdx.x & 63) == 0) red[threadIdx.x >> 6] = m;
    __syncthreads();
    m = fmaxf(fmaxf(red[0], red[1]), fmaxf(red[2], red[3]));
    __syncthreads();

    float e[8];
    e[0] = expf(v0.x - m); e[1] = expf(v0.y - m);
    e[2] = expf(v0.z - m); e[3] = expf(v0.w - m);
    e[4] = expf(v1.x - m); e[5] = expf(v1.y - m);
    e[6] = expf(v1.z - m); e[7] = expf(v1.w - m);

    float s = e[0] + e[1] + e[2] + e[3] + e[4] + e[5] + e[6] + e[7];
    #pragma unroll
    for (int off = 32; off > 0; off >>= 1) s += __shfl_xor(s, off);
    if ((threadIdx.x & 63) == 0) red[threadIdx.x >> 6] = s;
    __syncthreads();
    s = red[0] + red[1] + red[2] + red[3];

    float inv = 1.0f / s;
    out4[threadIdx.x]       = make_float4(e[0] * inv, e[1] * inv, e[2] * inv, e[3] * inv);
    out4[threadIdx.x + 256] = make_float4(e[4] * inv, e[5] * inv, e[6] * inv, e[7] * inv);
}

// ---------------------------------------------------------------------------
extern "C" void kernel_launch(void* const* d_in, const int* in_sizes, int n_in,
                              void* d_out, int out_size, void* d_ws, size_t ws_size,
                              hipStream_t stream)
{
    const float* x  = (const float*)d_in[0];   // [T_SEQ][EDIM]
    const float* Wh = (const float*)d_in[1];   // [HDIM][HDIM]
    const float* Wx = (const float*)d_in[2];   // [HDIM][EDIM]
    const float* Wy = (const float*)d_in[3];   // [EDIM][HDIM]
    const float* Bh = (const float*)d_in[4];   // [HDIM]
    const float* By = (const float*)d_in[5];   // [EDIM]

    float* out    = (float*)d_out;
    float* hfinal = out;                 // [HDIM]
    float* logits = out + HDIM;          // [T_SEQ][EDIM]: logits, then probs

    float* xpT  = (float*)d_ws;                                   // [HDIM][T_SEQ]
    u64*   hbuf = (u64*)((char*)d_ws + (size_t)T_SEQ * HDIM * 4); // [2][HDIM]

    // clear tagged h buffers so replays never see stale tags
    hipMemsetAsync(hbuf, 0, 2 * HDIM * sizeof(u64), stream);

    // Phase 1: xpT = (x @ Wx^T + Bh)^T   -> [HDIM][T_SEQ]
    gemm128_nt_bias_tc<<<dim3(HDIM / 128, T_SEQ / 128), 256, 0, stream>>>(
        x, Wx, Bh, xpT, T_SEQ, HDIM, EDIM);

    // Phase 2: recurrence + fused output projection (cooperative for
    // guaranteed co-residency of the 64 blocks)
    int T = T_SEQ;
    const float* Wh_c = Wh; const float* Wy_c = Wy; const float* By_c = By;
    const float* xpT_c = xpT;
    void* args[] = {(void*)&Wh_c, (void*)&Wy_c, (void*)&By_c, (void*)&xpT_c,
                    (void*)&hfinal, (void*)&logits, (void*)&hbuf, (void*)&T};
    hipLaunchCooperativeKernel((void*)rnn_recurrence, dim3(RBLK), dim3(512),
                               args, 0, stream);

    // Phase 3: softmax rows, in-place on the logits region of d_out
    softmax_rows<<<dim3(T_SEQ), 256, 0, stream>>>(logits, logits);
}

// Round 17
// 14339.526 us; speedup vs baseline: 2.4611x; 2.4611x over previous
//
#include <hip/hip_runtime.h>

#define T_SEQ 8192
#define HDIM  2048
#define EDIM  2048
#define RBLK  64                      // recurrence blocks
#define ROWS_PER_BLK (HDIM / RBLK)    // 32 rows/block, 4 rows/wave

typedef unsigned long long u64;
typedef __attribute__((ext_vector_type(4))) unsigned int u32x4;
typedef __attribute__((ext_vector_type(4))) float f32x4;

// two 16B agent-coherent loads + full drain (R9 proven poll)
__device__ inline void poll_pair(const u64* p0, const u64* p1, u32x4& a, u32x4& b) {
    asm volatile("global_load_dwordx4 %0, %2, off sc1\n\t"
                 "global_load_dwordx4 %1, %3, off sc1\n\t"
                 "s_waitcnt vmcnt(0)"
                 : "=v"(a), "=v"(b) : "v"(p0), "v"(p1) : "memory");
}

// Non-rematerializable 16B load: result MUST live in registers (asm output).
__device__ inline f32x4 ld_w16(const float* p) {
    f32x4 r;
    asm volatile("global_load_dwordx4 %0, %1, off" : "=v"(r) : "v"(p));
    return r;
}

// tanh via e^{2z}: clamp +-15, exp2, rcp (validated R8/R9: absmax unchanged)
__device__ inline float fast_tanh(float z) {
    float zc = fminf(fmaxf(z, -15.f), 15.f);
    float zs = zc * 2.88539008177792681f;   // 2*log2(e)
    float ez; asm("v_exp_f32 %0, %1" : "=v"(ez) : "v"(zs));
    float rc; float ezp = ez + 1.f;
    asm("v_rcp_f32 %0, %1" : "=v"(rc) : "v"(ezp));
    return (ez - 1.f) * rc;
}

// ---------------------------------------------------------------------------
// 128x128-tile GEMM (NT): C[m][n] = sum_k A[m][k]*B[n][k] + bias[n]  (R13)
// ---------------------------------------------------------------------------
__global__ __launch_bounds__(256) void gemm128_nt_bias(
    const float* __restrict__ A, const float* __restrict__ B,
    const float* __restrict__ bias, float* __restrict__ C,
    int M, int N, int K)
{
    __shared__ float As[16][128 + 4];
    __shared__ float Bs[16][128 + 4];

    const int tid = threadIdx.x;
    const int tx = tid & 15;
    const int ty = tid >> 4;
    const int m0 = blockIdx.y * 128;
    const int n0 = blockIdx.x * 128;

    float acc[8][8] = {};

    for (int kk = 0; kk < K; kk += 16) {
        #pragma unroll
        for (int p = 0; p < 2; ++p) {
            int idx = p * 256 + tid;
            int r  = idx >> 2;
            int cb = (idx & 3) * 4;
            float4 va = *(const float4*)&A[(size_t)(m0 + r) * K + kk + cb];
            As[cb + 0][r] = va.x; As[cb + 1][r] = va.y;
            As[cb + 2][r] = va.z; As[cb + 3][r] = va.w;
            float4 vb = *(const float4*)&B[(size_t)(n0 + r) * K + kk + cb];
            Bs[cb + 0][r] = vb.x; Bs[cb + 1][r] = vb.y;
            Bs[cb + 2][r] = vb.z; Bs[cb + 3][r] = vb.w;
        }
        __syncthreads();
        #pragma unroll
        for (int k = 0; k < 16; ++k) {
            float4 a0 = *(const float4*)&As[k][ty * 8];
            float4 a1 = *(const float4*)&As[k][ty * 8 + 4];
            float4 b0 = *(const float4*)&Bs[k][tx * 8];
            float4 b1 = *(const float4*)&Bs[k][tx * 8 + 4];
            float av[8] = {a0.x, a0.y, a0.z, a0.w, a1.x, a1.y, a1.z, a1.w};
            float bv[8] = {b0.x, b0.y, b0.z, b0.w, b1.x, b1.y, b1.z, b1.w};
            #pragma unroll
            for (int i = 0; i < 8; ++i)
                #pragma unroll
                for (int j = 0; j < 8; ++j)
                    acc[i][j] = fmaf(av[i], bv[j], acc[i][j]);
        }
        __syncthreads();
    }

    float4 bb0 = *(const float4*)&bias[n0 + tx * 8];
    float4 bb1 = *(const float4*)&bias[n0 + tx * 8 + 4];
    float bv[8] = {bb0.x, bb0.y, bb0.z, bb0.w, bb1.x, bb1.y, bb1.z, bb1.w};
    #pragma unroll
    for (int i = 0; i < 8; ++i) {
        float4 o0, o1;
        o0.x = acc[i][0] + bv[0]; o0.y = acc[i][1] + bv[1];
        o0.z = acc[i][2] + bv[2]; o0.w = acc[i][3] + bv[3];
        o1.x = acc[i][4] + bv[4]; o1.y = acc[i][5] + bv[5];
        o1.z = acc[i][6] + bv[6]; o1.w = acc[i][7] + bv[7];
        float* cp = &C[(size_t)(m0 + ty * 8 + i) * N + n0 + tx * 8];
        *(float4*)cp = o0;
        *(float4*)(cp + 4) = o1;
    }
}

// ---------------------------------------------------------------------------
// Same 128x128 GEMM, TRANSPOSED output: Ct[n][m] (xpT: 16 steps per line).
// ---------------------------------------------------------------------------
__global__ __launch_bounds__(256) void gemm128_nt_bias_tc(
    const float* __restrict__ A, const float* __restrict__ B,
    const float* __restrict__ bias, float* __restrict__ Ct,
    int M, int N, int K)
{
    __shared__ float As[16][128 + 4];
    __shared__ float Bs[16][128 + 4];

    const int tid = threadIdx.x;
    const int tx = tid & 15;
    const int ty = tid >> 4;
    const int m0 = blockIdx.y * 128;
    const int n0 = blockIdx.x * 128;

    float acc[8][8] = {};

    for (int kk = 0; kk < K; kk += 16) {
        #pragma unroll
        for (int p = 0; p < 2; ++p) {
            int idx = p * 256 + tid;
            int r  = idx >> 2;
            int cb = (idx & 3) * 4;
            float4 va = *(const float4*)&A[(size_t)(m0 + r) * K + kk + cb];
            As[cb + 0][r] = va.x; As[cb + 1][r] = va.y;
            As[cb + 2][r] = va.z; As[cb + 3][r] = va.w;
            float4 vb = *(const float4*)&B[(size_t)(n0 + r) * K + kk + cb];
            Bs[cb + 0][r] = vb.x; Bs[cb + 1][r] = vb.y;
            Bs[cb + 2][r] = vb.z; Bs[cb + 3][r] = vb.w;
        }
        __syncthreads();
        #pragma unroll
        for (int k = 0; k < 16; ++k) {
            float4 a0 = *(const float4*)&As[k][ty * 8];
            float4 a1 = *(const float4*)&As[k][ty * 8 + 4];
            float4 b0 = *(const float4*)&Bs[k][tx * 8];
            float4 b1 = *(const float4*)&Bs[k][tx * 8 + 4];
            float av[8] = {a0.x, a0.y, a0.z, a0.w, a1.x, a1.y, a1.z, a1.w};
            float bv[8] = {b0.x, b0.y, b0.z, b0.w, b1.x, b1.y, b1.z, b1.w};
            #pragma unroll
            for (int i = 0; i < 8; ++i)
                #pragma unroll
                for (int j = 0; j < 8; ++j)
                    acc[i][j] = fmaf(av[i], bv[j], acc[i][j]);
        }
        __syncthreads();
    }

    #pragma unroll
    for (int j = 0; j < 8; ++j) {
        float bb = bias[n0 + tx * 8 + j];
        float4 o0, o1;
        o0.x = acc[0][j] + bb; o0.y = acc[1][j] + bb;
        o0.z = acc[2][j] + bb; o0.w = acc[3][j] + bb;
        o1.x = acc[4][j] + bb; o1.y = acc[5][j] + bb;
        o1.z = acc[6][j] + bb; o1.w = acc[7][j] + bb;
        float* cp = &Ct[(size_t)(n0 + tx * 8 + j) * M + m0 + ty * 8];
        *(float4*)cp = o0;
        *(float4*)(cp + 4) = o1;
    }
}

// ---------------------------------------------------------------------------
// Recurrence — byte-identical to R9/R13 (proven best: 12.7 ms).
// 64 blocks x 512 threads; wave w owns rows b*32+w*4..+3; W_h in 128
// asm-loaded registers/lane. Sync: hbuf[2][HDIM] u64 (tag<<32|f32bits), tag
// travels with data; readers poll 16B sc1 loads; writers relaxed agent-scope
// atomic exchange. Overwrite of the recycled buffer is safe: a wave's tag-t
// store value-depends on ALL its step-(t-1) loads, and poll success requires
// all 2048 tag-t words.
// ---------------------------------------------------------------------------
__global__ __launch_bounds__(512, 1) void rnn_recurrence(
    const float* __restrict__ Wh, const float* __restrict__ xpT,
    float* __restrict__ Hs, u64* __restrict__ hbuf, int T)
{
    const int tid  = threadIdx.x;
    const int lane = tid & 63;
    const int wid  = tid >> 6;                              // 0..7
    const int r0   = blockIdx.x * ROWS_PER_BLK + wid * 4;   // wave's first row

    const float* wr0 = Wh + (size_t)(r0 + 0) * HDIM + lane * 4;
    const float* wr1 = Wh + (size_t)(r0 + 1) * HDIM + lane * 4;
    const float* wr2 = Wh + (size_t)(r0 + 2) * HDIM + lane * 4;
    const float* wr3 = Wh + (size_t)(r0 + 3) * HDIM + lane * 4;

    f32x4 w00 = ld_w16(wr0 + 0*256), w01 = ld_w16(wr0 + 1*256), w02 = ld_w16(wr0 + 2*256), w03 = ld_w16(wr0 + 3*256);
    f32x4 w04 = ld_w16(wr0 + 4*256), w05 = ld_w16(wr0 + 5*256), w06 = ld_w16(wr0 + 6*256), w07 = ld_w16(wr0 + 7*256);
    f32x4 w10 = ld_w16(wr1 + 0*256), w11 = ld_w16(wr1 + 1*256), w12 = ld_w16(wr1 + 2*256), w13 = ld_w16(wr1 + 3*256);
    f32x4 w14 = ld_w16(wr1 + 4*256), w15 = ld_w16(wr1 + 5*256), w16 = ld_w16(wr1 + 6*256), w17 = ld_w16(wr1 + 7*256);
    f32x4 w20 = ld_w16(wr2 + 0*256), w21 = ld_w16(wr2 + 1*256), w22 = ld_w16(wr2 + 2*256), w23 = ld_w16(wr2 + 3*256);
    f32x4 w24 = ld_w16(wr2 + 4*256), w25 = ld_w16(wr2 + 5*256), w26 = ld_w16(wr2 + 6*256), w27 = ld_w16(wr2 + 7*256);
    f32x4 w30 = ld_w16(wr3 + 0*256), w31 = ld_w16(wr3 + 1*256), w32 = ld_w16(wr3 + 2*256), w33 = ld_w16(wr3 + 3*256);
    f32x4 w34 = ld_w16(wr3 + 4*256), w35 = ld_w16(wr3 + 5*256), w36 = ld_w16(wr3 + 6*256), w37 = ld_w16(wr3 + 7*256);
    asm volatile("s_waitcnt vmcnt(0)" ::: "memory");

    __shared__ float hsm[HDIM];

    for (int t = 0; t < T; ++t) {
        float xq = 0.f;
        if (lane < 4) xq = xpT[(size_t)(r0 + lane) * T + t];

        float sv = 0.f;
        if (t > 0) {
            const u64* hb = hbuf + (size_t)(t & 1) * HDIM;
            const unsigned tg = (unsigned)t;
            const u64* p0 = hb + 2 * tid;
            const u64* p1 = hb + 1024 + 2 * tid;

            u32x4 a, b;
            poll_pair(p0, p1, a, b);
            while ((a.y != tg) | (a.w != tg) | (b.y != tg) | (b.w != tg))
                poll_pair(p0, p1, a, b);

            ((float2*)hsm)[tid] =
                make_float2(__uint_as_float(a.x), __uint_as_float(a.z));
            ((float2*)hsm)[tid + 512] =
                make_float2(__uint_as_float(b.x), __uint_as_float(b.z));
            __syncthreads();

            float s0 = 0.f, s1 = 0.f, s2 = 0.f, s3 = 0.f;
            #define RNN_STEP(IDX, WA, WB, WC, WD)                                   \
            {   float4 h4 = ((const float4*)hsm)[(IDX) * 64 + lane];                \
                s0 = fmaf(WA.x, h4.x, s0); s0 = fmaf(WA.y, h4.y, s0);               \
                s0 = fmaf(WA.z, h4.z, s0); s0 = fmaf(WA.w, h4.w, s0);               \
                s1 = fmaf(WB.x, h4.x, s1); s1 = fmaf(WB.y, h4.y, s1);               \
                s1 = fmaf(WB.z, h4.z, s1); s1 = fmaf(WB.w, h4.w, s1);               \
                s2 = fmaf(WC.x, h4.x, s2); s2 = fmaf(WC.y, h4.y, s2);               \
                s2 = fmaf(WC.z, h4.z, s2); s2 = fmaf(WC.w, h4.w, s2);               \
                s3 = fmaf(WD.x, h4.x, s3); s3 = fmaf(WD.y, h4.y, s3);               \
                s3 = fmaf(WD.z, h4.z, s3); s3 = fmaf(WD.w, h4.w, s3); }
            RNN_STEP(0, w00, w10, w20, w30)
            RNN_STEP(1, w01, w11, w21, w31)
            RNN_STEP(2, w02, w12, w22, w32)
            RNN_STEP(3, w03, w13, w23, w33)
            RNN_STEP(4, w04, w14, w24, w34)
            RNN_STEP(5, w05, w15, w25, w35)
            RNN_STEP(6, w06, w16, w26, w36)
            RNN_STEP(7, w07, w17, w27, w37)
            #undef RNN_STEP

            float fa = (lane & 1) ? s1 : s0;
            float fb = (lane & 1) ? s0 : s1;
            fa += __shfl_xor(fb, 1);
            float fc = (lane & 1) ? s3 : s2;
            float fd = (lane & 1) ? s2 : s3;
            fc += __shfl_xor(fd, 1);
            float fe = (lane & 2) ? fc : fa;
            float ff = (lane & 2) ? fa : fc;
            fe += __shfl_xor(ff, 2);
            #pragma unroll
            for (int off = 4; off < 64; off <<= 1) fe += __shfl_xor(fe, off);
            sv = fe;
        }

        if (lane < 4) {
            float hn = fast_tanh(sv + xq);
            u64 pk = ((u64)(unsigned)(t + 1) << 32) | (u64)__float_as_uint(hn);
            (void)__hip_atomic_exchange(
                &hbuf[(size_t)((t + 1) & 1) * HDIM + r0 + lane], pk,
                __ATOMIC_RELAXED, __HIP_MEMORY_SCOPE_AGENT);
            Hs[(size_t)t * HDIM + r0 + lane] = hn;
        }
    }
}

// ---------------------------------------------------------------------------
// Row softmax over EDIM=2048: one block (256 threads) per row.
// ---------------------------------------------------------------------------
__global__ __launch_bounds__(256) void softmax_rows(
    const float* __restrict__ logits, float* __restrict__ out)
{
    const int row = blockIdx.x;
    const float4* in4 = (const float4*)(logits + (size_t)row * EDIM);
    float4* out4 = (float4*)(out + (size_t)row * EDIM);

    float4 v0 = in4[threadIdx.x];
    float4 v1 = in4[threadIdx.x + 256];

    float m = fmaxf(fmaxf(fmaxf(v0.x, v0.y), fmaxf(v0.z, v0.w)),
                    fmaxf(fmaxf(v1.x, v1.y), fmaxf(v1.z, v1.w)));
    #pragma unroll
    for (int off = 32; off > 0; off >>= 1) m = fmaxf(m, __shfl_xor(m, off));

    __shared__ float red[4];
    if ((threadIdx.x & 63) == 0) red[threadIdx.x >> 6] = m;
    __syncthreads();
    m = fmaxf(fmaxf(red[0], red[1]), fmaxf(red[2], red[3]));
    __syncthreads();

    float e[8];
    e[0] = expf(v0.x - m); e[1] = expf(v0.y - m);
    e[2] = expf(v0.z - m); e[3] = expf(v0.w - m);
    e[4] = expf(v1.x - m); e[5] = expf(v1.y - m);
    e[6] = expf(v1.z - m); e[7] = expf(v1.w - m);

    float s = e[0] + e[1] + e[2] + e[3] + e[4] + e[5] + e[6] + e[7];
    #pragma unroll
    for (int off = 32; off > 0; off >>= 1) s += __shfl_xor(s, off);
    if ((threadIdx.x & 63) == 0) red[threadIdx.x >> 6] = s;
    __syncthreads();
    s = red[0] + red[1] + red[2] + red[3];

    float inv = 1.0f / s;
    out4[threadIdx.x]       = make_float4(e[0] * inv, e[1] * inv, e[2] * inv, e[3] * inv);
    out4[threadIdx.x + 256] = make_float4(e[4] * inv, e[5] * inv, e[6] * inv, e[7] * inv);
}

__global__ void copy_vec(const float* __restrict__ src, float* __restrict__ dst, int n)
{
    int i = blockIdx.x * blockDim.x + threadIdx.x;
    if (i < n) dst[i] = src[i];
}

// ---------------------------------------------------------------------------
extern "C" void kernel_launch(void* const* d_in, const int* in_sizes, int n_in,
                              void* d_out, int out_size, void* d_ws, size_t ws_size,
                              hipStream_t stream)
{
    const float* x  = (const float*)d_in[0];   // [T_SEQ][EDIM]
    const float* Wh = (const float*)d_in[1];   // [HDIM][HDIM]
    const float* Wx = (const float*)d_in[2];   // [HDIM][EDIM]
    const float* Wy = (const float*)d_in[3];   // [EDIM][HDIM]
    const float* Bh = (const float*)d_in[4];   // [HDIM]
    const float* By = (const float*)d_in[5];   // [EDIM]

    float* out    = (float*)d_out;
    float* hfinal = out;                 // [HDIM]
    float* hs     = out + HDIM;          // [T_SEQ][HDIM]: holds hs, then probs

    float* xpT  = (float*)d_ws;                                   // [HDIM][T_SEQ]
    u64*   hbuf = (u64*)((char*)d_ws + (size_t)T_SEQ * HDIM * 4); // [2][HDIM]
    float* logits = xpT;                 // reuse (xpT dead after recurrence)

    // clear tagged h buffers so replays never see stale tags
    hipMemsetAsync(hbuf, 0, 2 * HDIM * sizeof(u64), stream);

    // Phase 1: xpT = (x @ Wx^T + Bh)^T   -> [HDIM][T_SEQ]
    gemm128_nt_bias_tc<<<dim3(HDIM / 128, T_SEQ / 128), 256, 0, stream>>>(
        x, Wx, Bh, xpT, T_SEQ, HDIM, EDIM);

    // Phase 2: recurrence — cooperative launch only to guarantee co-residency
    int T = T_SEQ;
    const float* xpT_c = xpT;
    void* args[] = {(void*)&Wh, (void*)&xpT_c, (void*)&hs, (void*)&hbuf, (void*)&T};
    hipLaunchCooperativeKernel((void*)rnn_recurrence, dim3(RBLK), dim3(512),
                               args, 0, stream);

    // Phase 3: logits = hs @ Wy^T + By   (normal [T][E] layout)
    gemm128_nt_bias<<<dim3(EDIM / 128, T_SEQ / 128), 256, 0, stream>>>(
        hs, Wy, By, logits, T_SEQ, EDIM, HDIM);

    // Phase 4: h_final = hs[T-1] (before softmax overwrites hs region)
    copy_vec<<<dim3(HDIM / 256), 256, 0, stream>>>(
        hs + (size_t)(T_SEQ - 1) * HDIM, hfinal, HDIM);

    // Phase 5: softmax rows: logits (ws) -> output region of d_out
    softmax_rows<<<dim3(T_SEQ), 256, 0, stream>>>(logits, hs);
}

// Round 18
// 13242.021 us; speedup vs baseline: 2.6651x; 1.0829x over previous
//
#include <hip/hip_runtime.h>

#define T_SEQ 8192
#define HDIM  2048
#define EDIM  2048
#define RBLK  64                      // recurrence blocks
#define ROWS_PER_BLK (HDIM / RBLK)    // 32 rows/block, 4 rows/wave

typedef unsigned long long u64;
typedef __attribute__((ext_vector_type(4))) unsigned int u32x4;
typedef __attribute__((ext_vector_type(4))) float f32x4;
typedef __attribute__((ext_vector_type(8))) short bf16x8;
typedef __attribute__((ext_vector_type(4))) short s16x4;

// two 16B agent-coherent loads + full drain (R9/R13 proven poll)
__device__ inline void poll_pair(const u64* p0, const u64* p1, u32x4& a, u32x4& b) {
    asm volatile("global_load_dwordx4 %0, %2, off sc1\n\t"
                 "global_load_dwordx4 %1, %3, off sc1\n\t"
                 "s_waitcnt vmcnt(0)"
                 : "=v"(a), "=v"(b) : "v"(p0), "v"(p1) : "memory");
}

// Non-rematerializable 16B load: result MUST live in registers (asm output).
__device__ inline f32x4 ld_w16(const float* p) {
    f32x4 r;
    asm volatile("global_load_dwordx4 %0, %1, off" : "=v"(r) : "v"(p));
    return r;
}

// tanh via e^{2z}: clamp +-15, exp2, rcp (validated R8-R17: absmax unchanged)
__device__ inline float fast_tanh(float z) {
    float zc = fminf(fmaxf(z, -15.f), 15.f);
    float zs = zc * 2.88539008177792681f;   // 2*log2(e)
    float ez; asm("v_exp_f32 %0, %1" : "=v"(ez) : "v"(zs));
    float rc; float ezp = ez + 1.f;
    asm("v_rcp_f32 %0, %1" : "=v"(rc) : "v"(ezp));
    return (ez - 1.f) * rc;
}

__device__ inline unsigned bf16_rne(float x) {
    unsigned u = __float_as_uint(x);
    return (u + 0x7fffu + ((u >> 16) & 1u)) >> 16;
}
// split f32x4 into hi/lo bf16 quads (hi+lo captures ~17 mantissa bits)
__device__ inline void cvt_split4(float4 v, s16x4& h, s16x4& l) {
    float xs[4] = {v.x, v.y, v.z, v.w};
    #pragma unroll
    for (int i = 0; i < 4; ++i) {
        unsigned hb = bf16_rne(xs[i]);
        float hf = __uint_as_float(hb << 16);
        unsigned lb = bf16_rne(xs[i] - hf);
        h[i] = (short)hb; l[i] = (short)lb;
    }
}

// ---------------------------------------------------------------------------
// Split-precision bf16 MFMA GEMM (NT): C[m][n] = sum_k A[m][k]*B[n][k] + bias.
//   A*B ~= Ah*Bh + Ah*Bl + Al*Bh (3 passes, residual ~2^-17 relative).
//   128x128 tile, 256 thr = 4 waves, each wave a 64x64 quadrant via 4x4
//   mfma_f32_16x16x32_bf16 frags. LDS: bf16 hi/lo tiles [128][32], 16B-chunk
//   XOR swizzle (chunk ^ (row&3)) -> frag ds_read_b128 at the 8cy/KB floor.
//   Frag layouts: A/B lane l holds row (l&15), k-window (l>>4)*8..+8;
//   C/D (guide-verified): col = lane&15, row = (lane>>4)*4 + reg.
//   bias_per_row=1: bias[m] (xpT use); 0: bias[n] (logits use).
// ---------------------------------------------------------------------------
__global__ __launch_bounds__(256) void gemm_mfma_split(
    const float* __restrict__ A, const float* __restrict__ B,
    const float* __restrict__ bias, float* __restrict__ C,
    int M, int N, int K, int bias_per_row)
{
    __shared__ short Ah[128 * 32], Al[128 * 32];   // 8KB each
    __shared__ short Bh[128 * 32], Bl[128 * 32];   // 32KB total

    const int tid  = threadIdx.x;
    const int lane = tid & 63;
    const int wv   = tid >> 6;            // 0..3
    const int wm   = (wv & 1) * 64;       // wave quadrant offsets
    const int wn   = (wv >> 1) * 64;
    const int fr   = lane & 15;           // frag row
    const int fg   = lane >> 4;           // frag k-group (16B chunk)
    const int m0   = blockIdx.y * 128;
    const int n0   = blockIdx.x * 128;

    f32x4 acc[4][4] = {};                 // [mi][nj]

    for (int kk = 0; kk < K; kk += 32) {
        // ---- stage: each thread 4 float4 per operand, swizzled bf16 hi/lo ----
        #pragma unroll
        for (int p = 0; p < 4; ++p) {
            int idx = p * 256 + tid;            // 0..1023
            int r   = idx >> 3;                 // row 0..127
            int c4  = idx & 7;                  // float4 index (4 k each)
            int boff = r * 64 + ((((c4 >> 1) ^ (r & 3)) << 4)) + (c4 & 1) * 8;
            float4 va = *(const float4*)&A[(size_t)(m0 + r) * K + kk + c4 * 4];
            float4 vb = *(const float4*)&B[(size_t)(n0 + r) * K + kk + c4 * 4];
            s16x4 h, l;
            cvt_split4(va, h, l);
            *(s16x4*)((char*)Ah + boff) = h;
            *(s16x4*)((char*)Al + boff) = l;
            cvt_split4(vb, h, l);
            *(s16x4*)((char*)Bh + boff) = h;
            *(s16x4*)((char*)Bl + boff) = l;
        }
        __syncthreads();

        // ---- frag loads (swizzled chunk = fg ^ (fr&3), row-invariant) ----
        const int ch = (fg ^ (fr & 3)) << 4;
        bf16x8 ah[4], al[4], bh[4], bl[4];
        #pragma unroll
        for (int i = 0; i < 4; ++i) {
            int ar = (wm + i * 16 + fr) * 64 + ch;
            int br = (wn + i * 16 + fr) * 64 + ch;
            ah[i] = *(const bf16x8*)((const char*)Ah + ar);
            al[i] = *(const bf16x8*)((const char*)Al + ar);
            bh[i] = *(const bf16x8*)((const char*)Bh + br);
            bl[i] = *(const bf16x8*)((const char*)Bl + br);
        }

        #pragma unroll
        for (int i = 0; i < 4; ++i)
            #pragma unroll
            for (int j = 0; j < 4; ++j) {
                acc[i][j] = __builtin_amdgcn_mfma_f32_16x16x32_bf16(ah[i], bh[j], acc[i][j], 0, 0, 0);
                acc[i][j] = __builtin_amdgcn_mfma_f32_16x16x32_bf16(ah[i], bl[j], acc[i][j], 0, 0, 0);
                acc[i][j] = __builtin_amdgcn_mfma_f32_16x16x32_bf16(al[i], bh[j], acc[i][j], 0, 0, 0);
            }
        __syncthreads();
    }

    // ---- epilogue: C/D map col=lane&15, row=(lane>>4)*4+reg ----
    #pragma unroll
    for (int i = 0; i < 4; ++i) {
        #pragma unroll
        for (int r = 0; r < 4; ++r) {
            int row = m0 + wm + i * 16 + fg * 4 + r;
            float rb = bias_per_row ? bias[row] : 0.f;
            #pragma unroll
            for (int j = 0; j < 4; ++j) {
                int col = n0 + wn + j * 16 + fr;
                float bv = bias_per_row ? rb : bias[col];
                C[(size_t)row * N + col] = acc[i][j][r] + bv;
            }
        }
    }
}

// ---------------------------------------------------------------------------
// Recurrence — byte-identical to R9/R13/R17 (proven best: 12.7 ms).
// ---------------------------------------------------------------------------
__global__ __launch_bounds__(512, 1) void rnn_recurrence(
    const float* __restrict__ Wh, const float* __restrict__ xpT,
    float* __restrict__ Hs, u64* __restrict__ hbuf, int T)
{
    const int tid  = threadIdx.x;
    const int lane = tid & 63;
    const int wid  = tid >> 6;                              // 0..7
    const int r0   = blockIdx.x * ROWS_PER_BLK + wid * 4;   // wave's first row

    const float* wr0 = Wh + (size_t)(r0 + 0) * HDIM + lane * 4;
    const float* wr1 = Wh + (size_t)(r0 + 1) * HDIM + lane * 4;
    const float* wr2 = Wh + (size_t)(r0 + 2) * HDIM + lane * 4;
    const float* wr3 = Wh + (size_t)(r0 + 3) * HDIM + lane * 4;

    f32x4 w00 = ld_w16(wr0 + 0*256), w01 = ld_w16(wr0 + 1*256), w02 = ld_w16(wr0 + 2*256), w03 = ld_w16(wr0 + 3*256);
    f32x4 w04 = ld_w16(wr0 + 4*256), w05 = ld_w16(wr0 + 5*256), w06 = ld_w16(wr0 + 6*256), w07 = ld_w16(wr0 + 7*256);
    f32x4 w10 = ld_w16(wr1 + 0*256), w11 = ld_w16(wr1 + 1*256), w12 = ld_w16(wr1 + 2*256), w13 = ld_w16(wr1 + 3*256);
    f32x4 w14 = ld_w16(wr1 + 4*256), w15 = ld_w16(wr1 + 5*256), w16 = ld_w16(wr1 + 6*256), w17 = ld_w16(wr1 + 7*256);
    f32x4 w20 = ld_w16(wr2 + 0*256), w21 = ld_w16(wr2 + 1*256), w22 = ld_w16(wr2 + 2*256), w23 = ld_w16(wr2 + 3*256);
    f32x4 w24 = ld_w16(wr2 + 4*256), w25 = ld_w16(wr2 + 5*256), w26 = ld_w16(wr2 + 6*256), w27 = ld_w16(wr2 + 7*256);
    f32x4 w30 = ld_w16(wr3 + 0*256), w31 = ld_w16(wr3 + 1*256), w32 = ld_w16(wr3 + 2*256), w33 = ld_w16(wr3 + 3*256);
    f32x4 w34 = ld_w16(wr3 + 4*256), w35 = ld_w16(wr3 + 5*256), w36 = ld_w16(wr3 + 6*256), w37 = ld_w16(wr3 + 7*256);
    asm volatile("s_waitcnt vmcnt(0)" ::: "memory");

    __shared__ float hsm[HDIM];

    for (int t = 0; t < T; ++t) {
        float xq = 0.f;
        if (lane < 4) xq = xpT[(size_t)(r0 + lane) * T + t];

        float sv = 0.f;
        if (t > 0) {
            const u64* hb = hbuf + (size_t)(t & 1) * HDIM;
            const unsigned tg = (unsigned)t;
            const u64* p0 = hb + 2 * tid;
            const u64* p1 = hb + 1024 + 2 * tid;

            u32x4 a, b;
            poll_pair(p0, p1, a, b);
            while ((a.y != tg) | (a.w != tg) | (b.y != tg) | (b.w != tg))
                poll_pair(p0, p1, a, b);

            ((float2*)hsm)[tid] =
                make_float2(__uint_as_float(a.x), __uint_as_float(a.z));
            ((float2*)hsm)[tid + 512] =
                make_float2(__uint_as_float(b.x), __uint_as_float(b.z));
            __syncthreads();

            float s0 = 0.f, s1 = 0.f, s2 = 0.f, s3 = 0.f;
            #define RNN_STEP(IDX, WA, WB, WC, WD)                                   \
            {   float4 h4 = ((const float4*)hsm)[(IDX) * 64 + lane];                \
                s0 = fmaf(WA.x, h4.x, s0); s0 = fmaf(WA.y, h4.y, s0);               \
                s0 = fmaf(WA.z, h4.z, s0); s0 = fmaf(WA.w, h4.w, s0);               \
                s1 = fmaf(WB.x, h4.x, s1); s1 = fmaf(WB.y, h4.y, s1);               \
                s1 = fmaf(WB.z, h4.z, s1); s1 = fmaf(WB.w, h4.w, s1);               \
                s2 = fmaf(WC.x, h4.x, s2); s2 = fmaf(WC.y, h4.y, s2);               \
                s2 = fmaf(WC.z, h4.z, s2); s2 = fmaf(WC.w, h4.w, s2);               \
                s3 = fmaf(WD.x, h4.x, s3); s3 = fmaf(WD.y, h4.y, s3);               \
                s3 = fmaf(WD.z, h4.z, s3); s3 = fmaf(WD.w, h4.w, s3); }
            RNN_STEP(0, w00, w10, w20, w30)
            RNN_STEP(1, w01, w11, w21, w31)
            RNN_STEP(2, w02, w12, w22, w32)
            RNN_STEP(3, w03, w13, w23, w33)
            RNN_STEP(4, w04, w14, w24, w34)
            RNN_STEP(5, w05, w15, w25, w35)
            RNN_STEP(6, w06, w16, w26, w36)
            RNN_STEP(7, w07, w17, w27, w37)
            #undef RNN_STEP

            float fa = (lane & 1) ? s1 : s0;
            float fb = (lane & 1) ? s0 : s1;
            fa += __shfl_xor(fb, 1);
            float fc = (lane & 1) ? s3 : s2;
            float fd = (lane & 1) ? s2 : s3;
            fc += __shfl_xor(fd, 1);
            float fe = (lane & 2) ? fc : fa;
            float ff = (lane & 2) ? fa : fc;
            fe += __shfl_xor(ff, 2);
            #pragma unroll
            for (int off = 4; off < 64; off <<= 1) fe += __shfl_xor(fe, off);
            sv = fe;
        }

        if (lane < 4) {
            float hn = fast_tanh(sv + xq);
            u64 pk = ((u64)(unsigned)(t + 1) << 32) | (u64)__float_as_uint(hn);
            (void)__hip_atomic_exchange(
                &hbuf[(size_t)((t + 1) & 1) * HDIM + r0 + lane], pk,
                __ATOMIC_RELAXED, __HIP_MEMORY_SCOPE_AGENT);
            Hs[(size_t)t * HDIM + r0 + lane] = hn;
        }
    }
}

// ---------------------------------------------------------------------------
// Row softmax over EDIM=2048: one block (256 threads) per row.
// ---------------------------------------------------------------------------
__global__ __launch_bounds__(256) void softmax_rows(
    const float* __restrict__ logits, float* __restrict__ out)
{
    const int row = blockIdx.x;
    const float4* in4 = (const float4*)(logits + (size_t)row * EDIM);
    float4* out4 = (float4*)(out + (size_t)row * EDIM);

    float4 v0 = in4[threadIdx.x];
    float4 v1 = in4[threadIdx.x + 256];

    float m = fmaxf(fmaxf(fmaxf(v0.x, v0.y), fmaxf(v0.z, v0.w)),
                    fmaxf(fmaxf(v1.x, v1.y), fmaxf(v1.z, v1.w)));
    #pragma unroll
    for (int off = 32; off > 0; off >>= 1) m = fmaxf(m, __shfl_xor(m, off));

    __shared__ float red[4];
    if ((threadIdx.x & 63) == 0) red[threadIdx.x >> 6] = m;
    __syncthreads();
    m = fmaxf(fmaxf(red[0], red[1]), fmaxf(red[2], red[3]));
    __syncthreads();

    float e[8];
    e[0] = expf(v0.x - m); e[1] = expf(v0.y - m);
    e[2] = expf(v0.z - m); e[3] = expf(v0.w - m);
    e[4] = expf(v1.x - m); e[5] = expf(v1.y - m);
    e[6] = expf(v1.z - m); e[7] = expf(v1.w - m);

    float s = e[0] + e[1] + e[2] + e[3] + e[4] + e[5] + e[6] + e[7];
    #pragma unroll
    for (int off = 32; off > 0; off >>= 1) s += __shfl_xor(s, off);
    if ((threadIdx.x & 63) == 0) red[threadIdx.x >> 6] = s;
    __syncthreads();
    s = red[0] + red[1] + red[2] + red[3];

    float inv = 1.0f / s;
    out4[threadIdx.x]       = make_float4(e[0] * inv, e[1] * inv, e[2] * inv, e[3] * inv);
    out4[threadIdx.x + 256] = make_float4(e[4] * inv, e[5] * inv, e[6] * inv, e[7] * inv);
}

__global__ void copy_vec(const float* __restrict__ src, float* __restrict__ dst, int n)
{
    int i = blockIdx.x * blockDim.x + threadIdx.x;
    if (i < n) dst[i] = src[i];
}

// ---------------------------------------------------------------------------
extern "C" void kernel_launch(void* const* d_in, const int* in_sizes, int n_in,
                              void* d_out, int out_size, void* d_ws, size_t ws_size,
                              hipStream_t stream)
{
    const float* x  = (const float*)d_in[0];   // [T_SEQ][EDIM]
    const float* Wh = (const float*)d_in[1];   // [HDIM][HDIM]
    const float* Wx = (const float*)d_in[2];   // [HDIM][EDIM]
    const float* Wy = (const float*)d_in[3];   // [EDIM][HDIM]
    const float* Bh = (const float*)d_in[4];   // [HDIM]
    const float* By = (const float*)d_in[5];   // [EDIM]

    float* out    = (float*)d_out;
    float* hfinal = out;                 // [HDIM]
    float* hs     = out + HDIM;          // [T_SEQ][HDIM]: holds hs, then probs

    float* xpT  = (float*)d_ws;                                   // [HDIM][T_SEQ]
    u64*   hbuf = (u64*)((char*)d_ws + (size_t)T_SEQ * HDIM * 4); // [2][HDIM]
    float* logits = xpT;                 // reuse (xpT dead after recurrence)

    // clear tagged h buffers so replays never see stale tags
    hipMemsetAsync(hbuf, 0, 2 * HDIM * sizeof(u64), stream);

    // Phase 1: xpT[h][t] = Wx@x^T + Bh   (MFMA split: A=Wx M=HDIM, B=x N=T_SEQ)
    gemm_mfma_split<<<dim3(T_SEQ / 128, HDIM / 128), 256, 0, stream>>>(
        Wx, x, Bh, xpT, HDIM, T_SEQ, EDIM, 1);

    // Phase 2: recurrence — cooperative launch only to guarantee co-residency
    int T = T_SEQ;
    const float* xpT_c = xpT;
    void* args[] = {(void*)&Wh, (void*)&xpT_c, (void*)&hs, (void*)&hbuf, (void*)&T};
    hipLaunchCooperativeKernel((void*)rnn_recurrence, dim3(RBLK), dim3(512),
                               args, 0, stream);

    // Phase 3: logits = hs @ Wy^T + By   (MFMA split: A=hs M=T_SEQ, B=Wy N=EDIM)
    gemm_mfma_split<<<dim3(EDIM / 128, T_SEQ / 128), 256, 0, stream>>>(
        hs, Wy, By, logits, T_SEQ, EDIM, HDIM, 0);

    // Phase 4: h_final = hs[T-1] (before softmax overwrites hs region)
    copy_vec<<<dim3(HDIM / 256), 256, 0, stream>>>(
        hs + (size_t)(T_SEQ - 1) * HDIM, hfinal, HDIM);

    // Phase 5: softmax rows: logits (ws) -> output region of d_out
    softmax_rows<<<dim3(T_SEQ), 256, 0, stream>>>(logits, hs);
}